// Round 1
// baseline (784.034 us; speedup 1.0000x reference)
//
#include <hip/hip_runtime.h>
#include <hip/hip_bf16.h>

// Problem constants
#define C_DIM 256      // channels
#define SPAT 4096      // h*w = 64*64
#define HEADS_N 8
#define DHEAD 64
#define MEMTOK 4
#define TTOK 4100      // MEMTOK + SPAT
#define HID 512        // HEADS_N * DHEAD

// ---------------------------------------------------------------------------
// Kernel 1: RMSNorm over channel axis. xn[c,p] = x[c,p] * rsqrt(sum_c x^2) * 16 * (gamma[c]+1)
// One thread per pixel; loads coalesced across threads (contiguous p).
// ---------------------------------------------------------------------------
__global__ __launch_bounds__(256) void rmsnorm_kernel(const float* __restrict__ x,
                                                      const float* __restrict__ gamma,
                                                      float* __restrict__ xn) {
    int p = blockIdx.x * 256 + threadIdx.x;  // 0..4095
    float ss = 0.f;
    for (int c = 0; c < C_DIM; ++c) {
        float v = x[c * SPAT + p];
        ss += v * v;
    }
    float inv = rsqrtf(ss) * 16.0f;  // * sqrt(256) / norm
    for (int c = 0; c < C_DIM; ++c) {
        xn[c * SPAT + p] = x[c * SPAT + p] * inv * (gamma[c] + 1.0f);
    }
}

// ---------------------------------------------------------------------------
// Kernel 2: copy mem_kv (2,8,4,64) into k/v buffers rows 0..3
// k[h][t][d] layout: h*TTOK*64 + t*64 + d
// ---------------------------------------------------------------------------
__global__ __launch_bounds__(256) void memkv_copy(const float* __restrict__ mem,
                                                  float* __restrict__ kb,
                                                  float* __restrict__ vb) {
    int i = blockIdx.x * 256 + threadIdx.x;  // 0..4095
    int d = i & 63;
    int m = (i >> 6) & 3;
    int h = (i >> 8) & 7;
    int s = (i >> 11) & 1;
    float val = mem[i];
    float* dst = (s == 0) ? kb : vb;
    dst[(size_t)h * TTOK * 64 + m * 64 + d] = val;
}

// ---------------------------------------------------------------------------
// Kernel 3: QKV GEMM: qkv[o,p] = sum_c w[o,c]*xn[c,p], o in [0,1536), p in [0,4096)
// Tile 64(o) x 64(p), k-chunks of 16. Each thread computes 4x4 register tile.
// Outputs scattered directly into q[h][p][d] / k[h][4+p][d] / v[h][4+p][d].
// ---------------------------------------------------------------------------
__global__ __launch_bounds__(256) void qkv_gemm(const float* __restrict__ w,
                                                const float* __restrict__ xn,
                                                float* __restrict__ qb,
                                                float* __restrict__ kb,
                                                float* __restrict__ vb) {
    int tile_p = blockIdx.x;            // 0..63
    int tile_o = blockIdx.y;            // 0..23
    int o0 = tile_o * 64, p0 = tile_p * 64;
    __shared__ float wt[16][68];        // [lc][lo]
    __shared__ float xt[16][68];        // [lc][lp]
    int t = threadIdx.x;
    int tx = t & 15, ty = t >> 4;
    float acc[4][4];
#pragma unroll
    for (int i = 0; i < 4; ++i)
#pragma unroll
        for (int j = 0; j < 4; ++j) acc[i][j] = 0.f;

    for (int c0 = 0; c0 < C_DIM; c0 += 16) {
        __syncthreads();
        {   // load w tile (64 o x 16 c), store transposed
            int lo = t >> 2, lc4 = (t & 3) * 4;
            float4 wv = *(const float4*)&w[(size_t)(o0 + lo) * C_DIM + c0 + lc4];
            wt[lc4 + 0][lo] = wv.x; wt[lc4 + 1][lo] = wv.y;
            wt[lc4 + 2][lo] = wv.z; wt[lc4 + 3][lo] = wv.w;
        }
        {   // load xn tile (16 c x 64 p)
            int lc = t >> 4, lp4 = (t & 15) * 4;
            *(float4*)&xt[lc][lp4] = *(const float4*)&xn[(size_t)(c0 + lc) * SPAT + p0 + lp4];
        }
        __syncthreads();
#pragma unroll
        for (int lc = 0; lc < 16; ++lc) {
            float4 a4 = *(float4*)&wt[lc][tx * 4];
            float4 b4 = *(float4*)&xt[lc][ty * 4];
            float av[4] = {a4.x, a4.y, a4.z, a4.w};
            float bv[4] = {b4.x, b4.y, b4.z, b4.w};
#pragma unroll
            for (int i = 0; i < 4; ++i)
#pragma unroll
                for (int j = 0; j < 4; ++j) acc[i][j] += av[i] * bv[j];
        }
    }
    // store: o = o0 + tx*4+i -> section/head; d = o & 63 = tx*4+i (tiles are head-aligned)
    int sec = tile_o >> 3, h = tile_o & 7;
    float* dst; int toff;
    if (sec == 0)      { dst = qb + (size_t)h * SPAT * 64; toff = 0; }
    else if (sec == 1) { dst = kb + (size_t)h * TTOK * 64; toff = MEMTOK; }
    else               { dst = vb + (size_t)h * TTOK * 64; toff = MEMTOK; }
#pragma unroll
    for (int j = 0; j < 4; ++j) {
        int p = p0 + ty * 4 + j;
        float4 val = {acc[0][j], acc[1][j], acc[2][j], acc[3][j]};
        *(float4*)&dst[(size_t)(toff + p) * 64 + tx * 4] = val;
    }
}

// ---------------------------------------------------------------------------
// Kernel 4: flash attention (fp32). Block = 1 head x 64 q-rows. K/V tiles of 64.
// Thread (tx,ty): rows r=ty*4+i, S-cols jj=tx*4+j (also O d-cols d=tx*4+j).
// Online softmax with per-row running max/sum (== reference softmax: shift-invariant).
// ---------------------------------------------------------------------------
__global__ __launch_bounds__(256) void attn_kernel(const float* __restrict__ qb,
                                                   const float* __restrict__ kb,
                                                   const float* __restrict__ vb,
                                                   float* __restrict__ ob) {
    const int h = blockIdx.y;
    const int p0 = blockIdx.x * 64;
    const float* qh = qb + (size_t)h * SPAT * 64;
    const float* kh = kb + (size_t)h * TTOK * 64;
    const float* vh = vb + (size_t)h * TTOK * 64;
    float* oh = ob + (size_t)h * SPAT * 64;

    __shared__ float Qs[64][68];
    __shared__ float Ks[64][68];
    __shared__ float Vs[64][68];
    __shared__ float Ps[64][68];   // [jj][r]

    const int t = threadIdx.x;
    const int tx = t & 15, ty = t >> 4;

    {   // load Q tile
        int lr = t >> 2;
        int lc0 = (t & 3) * 16;
#pragma unroll
        for (int i = 0; i < 4; ++i)
            *(float4*)&Qs[lr][lc0 + i * 4] =
                *(const float4*)&qh[(size_t)(p0 + lr) * 64 + lc0 + i * 4];
    }

    float m_i[4], l_i[4], Oa[4][4];
#pragma unroll
    for (int i = 0; i < 4; ++i) {
        m_i[i] = -1e30f; l_i[i] = 0.f;
#pragma unroll
        for (int j = 0; j < 4; ++j) Oa[i][j] = 0.f;
    }

    for (int tile = 0; tile < 65; ++tile) {
        const int tbase = tile * 64;
        const int tcount = (tile < 64) ? 64 : (TTOK - 64 * 64);  // 64 or 4
        __syncthreads();  // previous PV reads of Ks/Vs/Ps complete
        {   // load K,V tiles (zero-pad past tcount)
            int lr = t >> 2;
            int lc0 = (t & 3) * 16;
            if (lr < tcount) {
#pragma unroll
                for (int i = 0; i < 4; ++i) {
                    *(float4*)&Ks[lr][lc0 + i * 4] =
                        *(const float4*)&kh[(size_t)(tbase + lr) * 64 + lc0 + i * 4];
                    *(float4*)&Vs[lr][lc0 + i * 4] =
                        *(const float4*)&vh[(size_t)(tbase + lr) * 64 + lc0 + i * 4];
                }
            } else {
                float4 z = {0.f, 0.f, 0.f, 0.f};
#pragma unroll
                for (int i = 0; i < 4; ++i) {
                    *(float4*)&Ks[lr][lc0 + i * 4] = z;
                    *(float4*)&Vs[lr][lc0 + i * 4] = z;
                }
            }
        }
        __syncthreads();

        // S = Q K^T (4x4 per thread)
        float s[4][4];
#pragma unroll
        for (int i = 0; i < 4; ++i)
#pragma unroll
            for (int j = 0; j < 4; ++j) s[i][j] = 0.f;
        for (int c = 0; c < 64; c += 4) {
            float4 q4[4], k4[4];
#pragma unroll
            for (int i = 0; i < 4; ++i) q4[i] = *(float4*)&Qs[ty * 4 + i][c];
#pragma unroll
            for (int j = 0; j < 4; ++j) k4[j] = *(float4*)&Ks[tx * 4 + j][c];
#pragma unroll
            for (int i = 0; i < 4; ++i)
#pragma unroll
                for (int j = 0; j < 4; ++j)
                    s[i][j] += q4[i].x * k4[j].x + q4[i].y * k4[j].y +
                               q4[i].z * k4[j].z + q4[i].w * k4[j].w;
        }
        // scale + mask OOB keys
#pragma unroll
        for (int i = 0; i < 4; ++i)
#pragma unroll
            for (int j = 0; j < 4; ++j)
                s[i][j] = (tx * 4 + j < tcount) ? s[i][j] * 0.125f : -1e30f;

        // online softmax update (rows spread over 16 tx-lanes)
#pragma unroll
        for (int i = 0; i < 4; ++i) {
            float rm = fmaxf(fmaxf(s[i][0], s[i][1]), fmaxf(s[i][2], s[i][3]));
#pragma unroll
            for (int off = 1; off < 16; off <<= 1) rm = fmaxf(rm, __shfl_xor(rm, off, 64));
            float mn = fmaxf(m_i[i], rm);
            float al = __expf(m_i[i] - mn);
            float rsum = 0.f;
#pragma unroll
            for (int j = 0; j < 4; ++j) {
                float pv = __expf(s[i][j] - mn);
                s[i][j] = pv;
                rsum += pv;
            }
#pragma unroll
            for (int off = 1; off < 16; off <<= 1) rsum += __shfl_xor(rsum, off, 64);
            l_i[i] = l_i[i] * al + rsum;
            m_i[i] = mn;
#pragma unroll
            for (int j = 0; j < 4; ++j) Oa[i][j] *= al;
        }

        // write P to LDS transposed: Ps[jj][r]
#pragma unroll
        for (int i = 0; i < 4; ++i)
#pragma unroll
            for (int j = 0; j < 4; ++j) Ps[tx * 4 + j][ty * 4 + i] = s[i][j];
        __syncthreads();

        // O += P V  (masked jj have P==0, safe to run full 64)
        for (int jj = 0; jj < 64; ++jj) {
            float4 p4 = *(float4*)&Ps[jj][ty * 4];  // rows ty*4..+3
            float4 v4 = *(float4*)&Vs[jj][tx * 4];  // dims tx*4..+3
            float pr[4] = {p4.x, p4.y, p4.z, p4.w};
            float vv[4] = {v4.x, v4.y, v4.z, v4.w};
#pragma unroll
            for (int i = 0; i < 4; ++i)
#pragma unroll
                for (int j = 0; j < 4; ++j) Oa[i][j] += pr[i] * vv[j];
        }
    }

    // epilogue: divide by l, store o[h][p][d]
#pragma unroll
    for (int i = 0; i < 4; ++i) {
        float inv = 1.0f / l_i[i];
        float4 val = {Oa[i][0] * inv, Oa[i][1] * inv, Oa[i][2] * inv, Oa[i][3] * inv};
        *(float4*)&oh[(size_t)(p0 + ty * 4 + i) * 64 + tx * 4] = val;
    }
}

// ---------------------------------------------------------------------------
// Kernel 5: out projection: out[oc,p] = sum_{h,d} w_out[oc, h*64+d] * ob[h][p][d]
// Tile 64(oc) x 64(p), k-chunks of 16 (each chunk within one head).
// ---------------------------------------------------------------------------
__global__ __launch_bounds__(256) void out_gemm(const float* __restrict__ w,
                                                const float* __restrict__ ob,
                                                float* __restrict__ out) {
    int p0 = blockIdx.x * 64;           // 0..63 tiles
    int o0 = blockIdx.y * 64;           // 0..3 tiles
    __shared__ float at[16][68];        // [lc][lo]
    __shared__ float bt[16][68];        // [lc][lp]
    int t = threadIdx.x;
    int tx = t & 15, ty = t >> 4;
    float acc[4][4];
#pragma unroll
    for (int i = 0; i < 4; ++i)
#pragma unroll
        for (int j = 0; j < 4; ++j) acc[i][j] = 0.f;

    for (int c0 = 0; c0 < HID; c0 += 16) {
        int hh = c0 >> 6;
        int d0 = c0 & 63;
        __syncthreads();
        {   // load w_out tile
            int lo = t >> 2, lc4 = (t & 3) * 4;
            float4 wv = *(const float4*)&w[(size_t)(o0 + lo) * HID + c0 + lc4];
            at[lc4 + 0][lo] = wv.x; at[lc4 + 1][lo] = wv.y;
            at[lc4 + 2][lo] = wv.z; at[lc4 + 3][lo] = wv.w;
        }
        {   // load ob tile: hid chunk = head hh, dims d0..d0+15; 64 pixels
            int lp = t >> 2, ld4 = (t & 3) * 4;
            float4 bv = *(const float4*)&ob[(size_t)hh * SPAT * 64 + (size_t)(p0 + lp) * 64 + d0 + ld4];
            bt[ld4 + 0][lp] = bv.x; bt[ld4 + 1][lp] = bv.y;
            bt[ld4 + 2][lp] = bv.z; bt[ld4 + 3][lp] = bv.w;
        }
        __syncthreads();
#pragma unroll
        for (int lc = 0; lc < 16; ++lc) {
            float4 a4 = *(float4*)&at[lc][tx * 4];
            float4 b4 = *(float4*)&bt[lc][ty * 4];
            float av[4] = {a4.x, a4.y, a4.z, a4.w};
            float bv[4] = {b4.x, b4.y, b4.z, b4.w};
#pragma unroll
            for (int i = 0; i < 4; ++i)
#pragma unroll
                for (int j = 0; j < 4; ++j) acc[i][j] += av[i] * bv[j];
        }
    }
#pragma unroll
    for (int i = 0; i < 4; ++i) {
        float4 val = {acc[i][0], acc[i][1], acc[i][2], acc[i][3]};
        *(float4*)&out[(size_t)(o0 + tx * 4 + i) * SPAT + p0 + ty * 4] = val;
    }
}

// ---------------------------------------------------------------------------
// Launch
// ---------------------------------------------------------------------------
extern "C" void kernel_launch(void* const* d_in, const int* in_sizes, int n_in,
                              void* d_out, int out_size, void* d_ws, size_t ws_size,
                              hipStream_t stream) {
    const float* x      = (const float*)d_in[0];
    const float* gamma  = (const float*)d_in[1];
    const float* mem_kv = (const float*)d_in[2];
    const float* w_qkv  = (const float*)d_in[3];
    const float* w_out  = (const float*)d_in[4];
    float* out = (float*)d_out;

    // workspace layout (floats): xn | q | k | v | o  = ~37.8 MB total
    float* xn = (float*)d_ws;
    float* qb = xn + (size_t)C_DIM * SPAT;             // 1,048,576
    float* kb = qb + (size_t)HEADS_N * SPAT * DHEAD;   // +2,097,152
    float* vb = kb + (size_t)HEADS_N * TTOK * DHEAD;   // +2,099,200
    float* ob = vb + (size_t)HEADS_N * TTOK * DHEAD;   // +2,099,200

    rmsnorm_kernel<<<dim3(16), 256, 0, stream>>>(x, gamma, xn);
    memkv_copy<<<dim3(16), 256, 0, stream>>>(mem_kv, kb, vb);
    qkv_gemm<<<dim3(64, 24), 256, 0, stream>>>(w_qkv, xn, qb, kb, vb);
    attn_kernel<<<dim3(64, 8), 256, 0, stream>>>(qb, kb, vb, ob);
    out_gemm<<<dim3(64, 4), 256, 0, stream>>>(w_out, ob, out);
}

// Round 2
// 289.568 us; speedup vs baseline: 2.7076x; 2.7076x over previous
//
#include <hip/hip_runtime.h>
#include <hip/hip_bf16.h>
#include <math.h>

// Problem constants
#define C_DIM 256      // channels
#define SPAT 4096      // h*w = 64*64
#define HEADS_N 8
#define DHEAD 64
#define MEMTOK 4
#define TTOK 4100      // MEMTOK + SPAT
#define TTOKP 4160     // padded to 65 tiles of 64
#define HID 512        // HEADS_N * DHEAD
#define PITCH 72       // LDS row pitch in bf16 elems (144 B -> 4-bank shift/row)

typedef __bf16 bf16x8 __attribute__((ext_vector_type(8)));
typedef unsigned short u16x8 __attribute__((ext_vector_type(8)));
typedef float f32x4 __attribute__((ext_vector_type(4)));

static __device__ inline unsigned short f2bf(float f) {  // RNE f32->bf16
    unsigned int u = __float_as_uint(f);
    u += 0x7fffu + ((u >> 16) & 1u);
    return (unsigned short)(u >> 16);
}

static __device__ inline bf16x8 ldb8(const unsigned short* p) {
    union { u16x8 u; bf16x8 b; } t;
    t.u = *(const u16x8*)p;
    return t.b;
}

// ---------------------------------------------------------------------------
// Kernel 1: RMSNorm over channel axis; 64 pixels/block, 4 channel-groups.
// ---------------------------------------------------------------------------
__global__ __launch_bounds__(256) void rmsnorm_kernel(const float* __restrict__ x,
                                                      const float* __restrict__ gamma,
                                                      float* __restrict__ xn) {
    int p = blockIdx.x * 64 + (threadIdx.x & 63);
    int g = threadIdx.x >> 6;           // 0..3 channel group
    float ss = 0.f;
    for (int c = g * 64; c < g * 64 + 64; ++c) {
        float v = x[c * SPAT + p];
        ss += v * v;
    }
    __shared__ float red[4][64];
    red[g][threadIdx.x & 63] = ss;
    __syncthreads();
    int lp = threadIdx.x & 63;
    float tot = red[0][lp] + red[1][lp] + red[2][lp] + red[3][lp];
    float inv = rsqrtf(tot) * 16.0f;    // * sqrt(256)/norm
    for (int c = g * 64; c < g * 64 + 64; ++c)
        xn[c * SPAT + p] = x[c * SPAT + p] * inv * (gamma[c] + 1.0f);
}

// ---------------------------------------------------------------------------
// Kernel 2: mem_kv copy (bf16) + zero-fill pad rows/cols (ws is re-poisoned!)
// kb: [h][TTOKP][64] bf16, rows 0..3 = mem k, rows 4100..4159 zero
// vtb: [h][64][TTOKP] bf16 (transposed), cols 0..3 = mem v, cols 4100.. zero
// ---------------------------------------------------------------------------
__global__ __launch_bounds__(256) void fixup_kernel(const float* __restrict__ mem,
                                                    unsigned short* __restrict__ kb,
                                                    unsigned short* __restrict__ vtb) {
    int i = blockIdx.x * 256 + threadIdx.x;
    if (i < 4096) {
        int d = i & 63, m = (i >> 6) & 3, h = (i >> 8) & 7, s = (i >> 11) & 1;
        unsigned short val = f2bf(mem[i]);
        if (s == 0) kb[(size_t)h * TTOKP * 64 + m * 64 + d] = val;
        else        vtb[((size_t)h * 64 + d) * TTOKP + m] = val;
    } else {
        int z = i - 4096;              // 0..61439
        if (z < 30720) {               // kb pad rows
            int h = z / 3840, r = z % 3840;
            int row = TTOK + r / 64, d = r % 64;
            kb[(size_t)h * TTOKP * 64 + row * 64 + d] = 0;
        } else {                       // vtb pad cols
            z -= 30720;
            int h = z / 3840, r = z % 3840;
            int d = r / 60, tcol = TTOK + r % 60;
            vtb[((size_t)h * 64 + d) * TTOKP + tcol] = 0;
        }
    }
}

// ---------------------------------------------------------------------------
// Kernel 3: QKV GEMM (fp32 compute, bf16 outputs).
// q section gets folded scale 0.125*log2(e) (softmax scale + exp2 domain).
// q: [h][4096][64]; k: [h][TTOKP][64] (rows 4..4099); v: [h][64][TTOKP] transposed.
// ---------------------------------------------------------------------------
__global__ __launch_bounds__(256) void qkv_gemm(const float* __restrict__ w,
                                                const float* __restrict__ xn,
                                                unsigned short* __restrict__ qb,
                                                unsigned short* __restrict__ kb,
                                                unsigned short* __restrict__ vtb) {
    int tile_p = blockIdx.x;            // 0..63
    int tile_o = blockIdx.y;            // 0..23
    int o0 = tile_o * 64, p0 = tile_p * 64;
    __shared__ float wt[16][68];        // [lc][lo]
    __shared__ float xt[16][68];        // [lc][lp]
    int t = threadIdx.x;
    int tx = t & 15, ty = t >> 4;
    float acc[4][4];
#pragma unroll
    for (int i = 0; i < 4; ++i)
#pragma unroll
        for (int j = 0; j < 4; ++j) acc[i][j] = 0.f;

    for (int c0 = 0; c0 < C_DIM; c0 += 16) {
        __syncthreads();
        {   // w tile (64 o x 16 c), transposed
            int lo = t >> 2, lc4 = (t & 3) * 4;
            float4 wv = *(const float4*)&w[(size_t)(o0 + lo) * C_DIM + c0 + lc4];
            wt[lc4 + 0][lo] = wv.x; wt[lc4 + 1][lo] = wv.y;
            wt[lc4 + 2][lo] = wv.z; wt[lc4 + 3][lo] = wv.w;
        }
        {   // xn tile (16 c x 64 p)
            int lc = t >> 4, lp4 = (t & 15) * 4;
            *(float4*)&xt[lc][lp4] = *(const float4*)&xn[(size_t)(c0 + lc) * SPAT + p0 + lp4];
        }
        __syncthreads();
#pragma unroll
        for (int lc = 0; lc < 16; ++lc) {
            float4 a4 = *(float4*)&wt[lc][tx * 4];
            float4 b4 = *(float4*)&xt[lc][ty * 4];
            float av[4] = {a4.x, a4.y, a4.z, a4.w};
            float bv[4] = {b4.x, b4.y, b4.z, b4.w};
#pragma unroll
            for (int i = 0; i < 4; ++i)
#pragma unroll
                for (int j = 0; j < 4; ++j) acc[i][j] += av[i] * bv[j];
        }
    }
    int sec = tile_o >> 3, h = tile_o & 7;
    if (sec == 0) {
        const float QSC = 0.125f * 1.4426950408889634f;
        unsigned short* dst = qb + (size_t)h * SPAT * 64;
#pragma unroll
        for (int j = 0; j < 4; ++j) {
            int p = p0 + ty * 4 + j;
            ushort4 val = {f2bf(acc[0][j] * QSC), f2bf(acc[1][j] * QSC),
                           f2bf(acc[2][j] * QSC), f2bf(acc[3][j] * QSC)};
            *(ushort4*)&dst[(size_t)p * 64 + tx * 4] = val;
        }
    } else if (sec == 1) {
        unsigned short* dst = kb + (size_t)h * TTOKP * 64;
#pragma unroll
        for (int j = 0; j < 4; ++j) {
            int tt = MEMTOK + p0 + ty * 4 + j;
            ushort4 val = {f2bf(acc[0][j]), f2bf(acc[1][j]),
                           f2bf(acc[2][j]), f2bf(acc[3][j])};
            *(ushort4*)&dst[(size_t)tt * 64 + tx * 4] = val;
        }
    } else {  // v transposed: [d][t]
        unsigned short* dst = vtb + (size_t)h * 64 * TTOKP;
        int t0 = MEMTOK + p0 + ty * 4;
#pragma unroll
        for (int i = 0; i < 4; ++i) {
            int d = tx * 4 + i;
            ushort4 val = {f2bf(acc[i][0]), f2bf(acc[i][1]),
                           f2bf(acc[i][2]), f2bf(acc[i][3])};
            *(ushort4*)&dst[(size_t)d * TTOKP + t0] = val;
        }
    }
}

// ---------------------------------------------------------------------------
// Kernel 4: flash attention, bf16 MFMA (16x16x32), fp32 accum.
// Block = 1 head x 64 q-rows; 4 waves x 16 rows. K/V tiles of 64.
// Q pre-scaled by 0.125*log2e -> softmax in exp2 domain.
// ---------------------------------------------------------------------------
__global__ __launch_bounds__(256) void attn_mfma(const unsigned short* __restrict__ qb,
                                                 const unsigned short* __restrict__ kb,
                                                 const unsigned short* __restrict__ vtb,
                                                 float* __restrict__ ob) {
    const int h = blockIdx.y;
    const int p0 = blockIdx.x * 64;
    __shared__ unsigned short Qs[64 * PITCH];
    __shared__ unsigned short Ks[64 * PITCH];
    __shared__ unsigned short Vts[64 * PITCH];   // [d][key]
    __shared__ unsigned short Ps[4 * 16 * PITCH];

    const int t = threadIdx.x;
    const int w = t >> 6;
    const int lane = t & 63;
    const int col16 = lane & 15;
    const int quad = lane >> 4;

    const unsigned short* qh = qb + (size_t)h * SPAT * 64;
    const unsigned short* kh = kb + (size_t)h * TTOKP * 64;
    const unsigned short* vh = vtb + (size_t)h * 64 * TTOKP;
    float* oh = ob + ((size_t)h * SPAT + p0) * 64;

    // stage Q tile (64 rows x 64 bf16)
#pragma unroll
    for (int c = t; c < 512; c += 256) {
        int row = c >> 3, off = (c & 7) * 8;
        *(u16x8*)&Qs[row * PITCH + off] = *(const u16x8*)&qh[(size_t)(p0 + row) * 64 + off];
    }

    f32x4 Oa[4];
    float m_i[4], l_i[4];
#pragma unroll
    for (int r = 0; r < 4; ++r) { m_i[r] = -1e30f; l_i[r] = 0.f; }
#pragma unroll
    for (int nt = 0; nt < 4; ++nt) Oa[nt] = (f32x4){0.f, 0.f, 0.f, 0.f};

    for (int tile = 0; tile < 65; ++tile) {
        const int tbase = tile * 64;
        __syncthreads();   // prev-tile reads of Ks/Vts done (also Q ready at tile 0)
#pragma unroll
        for (int c = t; c < 512; c += 256) {
            int row = c >> 3, off = (c & 7) * 8;
            *(u16x8*)&Ks[row * PITCH + off] =
                *(const u16x8*)&kh[(size_t)(tbase + row) * 64 + off];
            *(u16x8*)&Vts[row * PITCH + off] =
                *(const u16x8*)&vh[(size_t)row * TTOKP + tbase + off];
        }
        __syncthreads();

        // S = Q K^T  (wave rows w*16..w*16+15, keys tbase..tbase+63)
        f32x4 sv[4];
#pragma unroll
        for (int nt = 0; nt < 4; ++nt) sv[nt] = (f32x4){0.f, 0.f, 0.f, 0.f};
        bf16x8 aq0 = ldb8(&Qs[(w * 16 + col16) * PITCH + quad * 8]);
        bf16x8 aq1 = ldb8(&Qs[(w * 16 + col16) * PITCH + 32 + quad * 8]);
#pragma unroll
        for (int nt = 0; nt < 4; ++nt) {
            bf16x8 bk0 = ldb8(&Ks[(nt * 16 + col16) * PITCH + quad * 8]);
            bf16x8 bk1 = ldb8(&Ks[(nt * 16 + col16) * PITCH + 32 + quad * 8]);
            sv[nt] = __builtin_amdgcn_mfma_f32_16x16x32_bf16(aq0, bk0, sv[nt], 0, 0, 0);
            sv[nt] = __builtin_amdgcn_mfma_f32_16x16x32_bf16(aq1, bk1, sv[nt], 0, 0, 0);
        }

        if (tile == 64) {   // mask invalid keys (only 4 valid in last tile)
#pragma unroll
            for (int nt = 0; nt < 4; ++nt)
#pragma unroll
                for (int r = 0; r < 4; ++r)
                    if (nt * 16 + col16 >= TTOK - 64 * 64) sv[nt][r] = -1e30f;
        }

        // online softmax (exp2 domain); row = quad*4+r, 16 cols per quad-lane-group
        float alpha[4];
#pragma unroll
        for (int r = 0; r < 4; ++r) {
            float rm = fmaxf(fmaxf(sv[0][r], sv[1][r]), fmaxf(sv[2][r], sv[3][r]));
            rm = fmaxf(rm, __shfl_xor(rm, 1, 64));
            rm = fmaxf(rm, __shfl_xor(rm, 2, 64));
            rm = fmaxf(rm, __shfl_xor(rm, 4, 64));
            rm = fmaxf(rm, __shfl_xor(rm, 8, 64));
            float mn = fmaxf(m_i[r], rm);
            alpha[r] = __builtin_amdgcn_exp2f(m_i[r] - mn);
            m_i[r] = mn;
            float rs = 0.f;
#pragma unroll
            for (int nt = 0; nt < 4; ++nt) {
                float pv = __builtin_amdgcn_exp2f(sv[nt][r] - mn);
                sv[nt][r] = pv;
                rs += pv;
            }
            rs += __shfl_xor(rs, 1, 64);
            rs += __shfl_xor(rs, 2, 64);
            rs += __shfl_xor(rs, 4, 64);
            rs += __shfl_xor(rs, 8, 64);
            l_i[r] = l_i[r] * alpha[r] + rs;
        }
#pragma unroll
        for (int nt = 0; nt < 4; ++nt) {
            Oa[nt][0] *= alpha[0]; Oa[nt][1] *= alpha[1];
            Oa[nt][2] *= alpha[2]; Oa[nt][3] *= alpha[3];
        }

        // P: C-layout -> LDS -> A-layout (per-wave region, no barrier needed)
        unsigned short* pw = &Ps[w * 16 * PITCH];
#pragma unroll
        for (int nt = 0; nt < 4; ++nt)
#pragma unroll
            for (int r = 0; r < 4; ++r)
                pw[(quad * 4 + r) * PITCH + nt * 16 + col16] = f2bf(sv[nt][r]);

        bf16x8 pa0 = ldb8(&pw[col16 * PITCH + quad * 8]);
        bf16x8 pa1 = ldb8(&pw[col16 * PITCH + 32 + quad * 8]);

        // O += P V   (V in Vts[d][key]; B[k][n] = Vts[n][k])
#pragma unroll
        for (int nt = 0; nt < 4; ++nt) {
            bf16x8 bv0 = ldb8(&Vts[(nt * 16 + col16) * PITCH + quad * 8]);
            bf16x8 bv1 = ldb8(&Vts[(nt * 16 + col16) * PITCH + 32 + quad * 8]);
            Oa[nt] = __builtin_amdgcn_mfma_f32_16x16x32_bf16(pa0, bv0, Oa[nt], 0, 0, 0);
            Oa[nt] = __builtin_amdgcn_mfma_f32_16x16x32_bf16(pa1, bv1, Oa[nt], 0, 0, 0);
        }
    }

    // epilogue: O /= l, store [h][p][d] fp32
    float inv[4];
#pragma unroll
    for (int r = 0; r < 4; ++r) inv[r] = 1.0f / l_i[r];
#pragma unroll
    for (int nt = 0; nt < 4; ++nt)
#pragma unroll
        for (int r = 0; r < 4; ++r)
            oh[(size_t)(w * 16 + quad * 4 + r) * 64 + nt * 16 + col16] = Oa[nt][r] * inv[r];
}

// ---------------------------------------------------------------------------
// Kernel 5: out projection (fp32): out[oc,p] = sum_{h,d} w_out[oc,h*64+d]*ob[h][p][d]
// ---------------------------------------------------------------------------
__global__ __launch_bounds__(256) void out_gemm(const float* __restrict__ w,
                                                const float* __restrict__ ob,
                                                float* __restrict__ out) {
    int p0 = blockIdx.x * 64;
    int o0 = blockIdx.y * 64;
    __shared__ float at[16][68];
    __shared__ float bt[16][68];
    int t = threadIdx.x;
    int tx = t & 15, ty = t >> 4;
    float acc[4][4];
#pragma unroll
    for (int i = 0; i < 4; ++i)
#pragma unroll
        for (int j = 0; j < 4; ++j) acc[i][j] = 0.f;

    for (int c0 = 0; c0 < HID; c0 += 16) {
        int hh = c0 >> 6;
        int d0 = c0 & 63;
        __syncthreads();
        {
            int lo = t >> 2, lc4 = (t & 3) * 4;
            float4 wv = *(const float4*)&w[(size_t)(o0 + lo) * HID + c0 + lc4];
            at[lc4 + 0][lo] = wv.x; at[lc4 + 1][lo] = wv.y;
            at[lc4 + 2][lo] = wv.z; at[lc4 + 3][lo] = wv.w;
        }
        {
            int lp = t >> 2, ld4 = (t & 3) * 4;
            float4 bv = *(const float4*)&ob[(size_t)hh * SPAT * 64 + (size_t)(p0 + lp) * 64 + d0 + ld4];
            bt[ld4 + 0][lp] = bv.x; bt[ld4 + 1][lp] = bv.y;
            bt[ld4 + 2][lp] = bv.z; bt[ld4 + 3][lp] = bv.w;
        }
        __syncthreads();
#pragma unroll
        for (int lc = 0; lc < 16; ++lc) {
            float4 a4 = *(float4*)&at[lc][tx * 4];
            float4 b4 = *(float4*)&bt[lc][ty * 4];
            float av[4] = {a4.x, a4.y, a4.z, a4.w};
            float bv[4] = {b4.x, b4.y, b4.z, b4.w};
#pragma unroll
            for (int i = 0; i < 4; ++i)
#pragma unroll
                for (int j = 0; j < 4; ++j) acc[i][j] += av[i] * bv[j];
        }
    }
#pragma unroll
    for (int i = 0; i < 4; ++i) {
        float4 val = {acc[i][0], acc[i][1], acc[i][2], acc[i][3]};
        *(float4*)&out[(size_t)(o0 + tx * 4 + i) * SPAT + p0 + ty * 4] = val;
    }
}

// ---------------------------------------------------------------------------
// Launch
// ---------------------------------------------------------------------------
extern "C" void kernel_launch(void* const* d_in, const int* in_sizes, int n_in,
                              void* d_out, int out_size, void* d_ws, size_t ws_size,
                              hipStream_t stream) {
    const float* x      = (const float*)d_in[0];
    const float* gamma  = (const float*)d_in[1];
    const float* mem_kv = (const float*)d_in[2];
    const float* w_qkv  = (const float*)d_in[3];
    const float* w_out  = (const float*)d_in[4];
    float* out = (float*)d_out;

    // workspace: xn(f32) | qb(bf16) | kb(bf16) | vtb(bf16) | ob(f32)  ~25 MB
    float* xn = (float*)d_ws;
    unsigned short* qb  = (unsigned short*)(xn + (size_t)C_DIM * SPAT);
    unsigned short* kb  = qb + (size_t)HEADS_N * SPAT * DHEAD;
    unsigned short* vtb = kb + (size_t)HEADS_N * TTOKP * DHEAD;
    float* ob = (float*)(vtb + (size_t)HEADS_N * DHEAD * TTOKP);

    rmsnorm_kernel<<<dim3(64), 256, 0, stream>>>(x, gamma, xn);
    fixup_kernel<<<dim3(256), 256, 0, stream>>>(mem_kv, kb, vtb);
    qkv_gemm<<<dim3(64, 24), 256, 0, stream>>>(w_qkv, xn, qb, kb, vtb);
    attn_mfma<<<dim3(64, 8), 256, 0, stream>>>(qb, kb, vtb, ob);
    out_gemm<<<dim3(64, 4), 256, 0, stream>>>(w_out, ob, out);
}